// Round 13
// baseline (134.269 us; speedup 1.0000x reference)
//
#include <hip/hip_runtime.h>
#include <stdint.h>

typedef short s16;
typedef __attribute__((ext_vector_type(8))) short short8;  // 8 bf16 (4 VGPRs)
typedef __attribute__((ext_vector_type(4))) float f32x4;

__device__ __forceinline__ s16 f2bf(float f) {
  union { float f; uint32_t u; } v; v.f = f;
  uint32_t u = v.u;
  uint32_t r = (u + 0x7fffu + ((u >> 16) & 1u)) >> 16;  // RNE
  return (s16)(uint16_t)r;
}
__device__ __forceinline__ float bf2f(s16 b) {
  union { uint32_t u; float f; } v; v.u = ((uint32_t)(uint16_t)b) << 16;
  return v.f;
}

#define GLOBAL_AS __attribute__((address_space(1)))
#define LDS_AS    __attribute__((address_space(3)))
__device__ __forceinline__ void gload_lds16(const void* g, void* l) {
  __builtin_amdgcn_global_load_lds((const GLOBAL_AS uint32_t*)g, (LDS_AS uint32_t*)l, 16, 0, 0);
}

// ---------------- GEMM body: C(MxN) = A(MxK,row) @ B, B given as BT(NxK,row) --
// PROVEN single-buffer 2-barrier K-loop, BK=64, XOR-swizzled LDS via
// pre-swizzled global source. Verbatim since round 3.
template<int BM_, int BN_, bool SX>
__device__ __forceinline__ void
gemm_body(const s16* __restrict__ A, const s16* __restrict__ BT,
          int M, int N, int K, int Kc, int bxi, int byi, int bzi,
          const float* __restrict__ rowscale,
          const s16* __restrict__ addend_bf,   // read-only; may equal A
          s16* __restrict__ obf_n, s16* __restrict__ obf_t,
          s16* lta, s16* ltb)
{
  constexpr int SWA = BM_ / 32;
  constexpr int SWB = BN_ / 32;
  constexpr int WM  = BM_ / 2;
  constexpr int WN  = BN_ / 2;
  constexpr int IM  = WM / 16;
  constexpr int JN  = WN / 16;

  const int tid  = threadIdx.x;
  const int lane = tid & 63;
  const int wave = tid >> 6;
  const int wr = wave >> 1, wc = wave & 1;
  const int bm0 = (SX ? bxi : byi) * BM_;
  const int bn0 = (SX ? byi : bxi) * BN_;
  const int k0  = bzi * Kc;

  f32x4 acc[IM][JN];
  #pragma unroll
  for (int i = 0; i < IM; ++i)
    #pragma unroll
    for (int j = 0; j < JN; ++j)
      #pragma unroll
      for (int r = 0; r < 4; ++r) acc[i][j][r] = 0.0f;

  const int lrow = lane >> 3;
  const int lke  = ((lane & 7) ^ lrow) * 8;
  const s16* Ab = A  + (size_t)(bm0 + wave * 8 + lrow) * K + k0 + lke;
  const s16* Bb = BT + (size_t)(bn0 + wave * 8 + lrow) * K + k0 + lke;

  const int fr = lane & 15;
  const int k8 = (lane >> 4) * 8;
  const int sw = (fr & 7) * 8;       // read-side XOR: row&7 == fr&7

  const int nt = Kc / 64;
  for (int t = 0; t < nt; ++t) {
    const int ko = t * 64;
    #pragma unroll
    for (int s = 0; s < SWA; ++s)
      gload_lds16(Ab + (size_t)s * 32 * K + ko, &lta[s * 2048 + wave * 512]);
    #pragma unroll
    for (int s = 0; s < SWB; ++s)
      gload_lds16(Bb + (size_t)s * 32 * K + ko, &ltb[s * 2048 + wave * 512]);
    __syncthreads();   // drains vmcnt(0): tile fully staged

    short8 af[2][IM], bfv[2][JN];
    #pragma unroll
    for (int kk = 0; kk < 2; ++kk) {
      #pragma unroll
      for (int i = 0; i < IM; ++i)
        af[kk][i] = *(const short8*)&lta[(wr * WM + i * 16 + fr) * 64 + ((kk * 32 + k8) ^ sw)];
      #pragma unroll
      for (int j = 0; j < JN; ++j)
        bfv[kk][j] = *(const short8*)&ltb[(wc * WN + j * 16 + fr) * 64 + ((kk * 32 + k8) ^ sw)];
    }
    #pragma unroll
    for (int kk = 0; kk < 2; ++kk)
      #pragma unroll
      for (int i = 0; i < IM; ++i)
        #pragma unroll
        for (int j = 0; j < JN; ++j)
          acc[i][j] = __builtin_amdgcn_mfma_f32_16x16x32_bf16(af[kk][i], bfv[kk][j], acc[i][j], 0, 0, 0);
    __syncthreads();   // all waves done reading before next tile overwrites
  }

  // epilogue — C/D layout: col = lane&15, row = (lane>>4)*4 + reg
  s16* on = obf_n ? obf_n + (size_t)bzi * M * N : nullptr;
  const int r0 = (lane >> 4) * 4;
  const int cl = lane & 15;
  #pragma unroll
  for (int i = 0; i < IM; ++i) {
    const int gm = bm0 + wr * WM + i * 16 + r0;
    #pragma unroll
    for (int j = 0; j < JN; ++j) {
      const int gn = bn0 + wc * WN + j * 16 + cl;
      #pragma unroll
      for (int r = 0; r < 4; ++r) {
        const size_t idx = (size_t)(gm + r) * N + gn;
        float v = acc[i][j][r];
        if (rowscale)  v *= rowscale[gm + r];
        if (addend_bf) v += bf2f(addend_bf[idx]);
        if (on)    on[idx] = f2bf(v);
        if (obf_t) obf_t[(size_t)gn * M + (gm + r)] = f2bf(v);
      }
    }
  }
}

// ------- standalone GEMM wrapper -------------------------------------------
// MAP=1: 1D grid, XCD-aware decode with the SMALL dim fastest: fid%8 ->
// (K-slice z = c&3, big-half = c>>2); within an XCD, byi = tt % gy varies
// fastest so the gy consecutive blocks share ONE big-operand panel ->
// panel stays L2-resident (working set ~1.3 MB << 4 MB). Round-12's decode
// had the big dim fastest: panel evicted before reuse, staging went to L3.
template<int BM_, int BN_, bool SX, int MAP>
__global__ void __launch_bounds__(256, 2)
gemm_t(const s16* __restrict__ A, const s16* __restrict__ BT,
       int M, int N, int K, int Kc, int gx, int gy,
       const float* __restrict__ rowscale,
       const s16* __restrict__ addend_bf,
       s16* __restrict__ obf_n, s16* __restrict__ obf_t)
{
  __shared__ alignas(16) s16 lds[BM_ * 64 + BN_ * 64];
  int bxi, byi, bzi;
  if (MAP == 1) {
    const int fid = blockIdx.x;
    const int c  = fid & 7;
    const int tt = fid >> 3;
    const int gxh = gx >> 1;
    bzi = c & 3;
    byi = tt % gy;                       // small dim fastest: L2 panel reuse
    bxi = (c >> 2) * gxh + tt / gy;
  } else {
    bxi = blockIdx.x; byi = blockIdx.y; bzi = blockIdx.z;
  }
  gemm_body<BM_, BN_, SX>(A, BT, M, N, K, Kc, bxi, byi, bzi,
                          rowscale, addend_bf, obf_n, obf_t, lds, lds + BM_ * 64);
}

// ------- mega1: st5 GEMM (St0 partials) + FtF GEMM (partials) ----------------
__global__ void __launch_bounds__(256, 2)
k_mega1(const s16* __restrict__ QT, const s16* __restrict__ Xb,
        const s16* __restrict__ FT, int m, int n,
        s16* __restrict__ parts_mn, s16* __restrict__ parts_mm)
{
  __shared__ alignas(16) s16 lds[192 * 64];   // 24.5 KB (max of both paths)
  int b = blockIdx.x;
  const int gx = n / 128;
  const int gy = m / 64;
  const int nSt5 = gx * gy * 4;               // 1024
  if (b < nSt5) {
    const int c = b & 7, tt = b >> 3, gxh = gx >> 1;
    const int bzi = c & 3;
    const int byi = tt % gy;                  // small dim fastest (L2 reuse)
    const int bxi = (c >> 2) * gxh + tt / gy;
    gemm_body<128, 64, true>(QT, Xb, n, m, n, n / 4, bxi, byi, bzi,
                             nullptr, nullptr, parts_mn, nullptr,
                             lds, lds + 128 * 64);
  } else {
    b -= nSt5;
    const int gm = m / 64;                    // 8
    const int bxi = b % gm, byi = (b / gm) % gm, bzi = b / (gm * gm);
    gemm_body<64, 64, false>(FT, FT, m, m, m, m / 4, bxi, byi, bzi,
                             nullptr, nullptr, parts_mm, nullptr,
                             lds, lds + 64 * 64);
  }
}

// ------- mega2: combine(St0)->Sb0  +  combine(FtF)->ghat + Frobenius ---------
// Last-arriving frob block computes rn = 1/(||FtF||_F+eps) and folds it into
// the doubling rowscales scal0 = 0.8*lam*rn, scal1 = scal0^2.
__global__ void __launch_bounds__(256)
k_mega2(const s16* __restrict__ parts_mn, const s16* __restrict__ parts_mm,
        const float* __restrict__ lam, int m, int n,
        s16* __restrict__ Sb0, s16* __restrict__ ghat,
        float* __restrict__ partial, float* __restrict__ scal,
        unsigned int* __restrict__ counter)
{
  const size_t MN = (size_t)m * n;
  const int tid = threadIdx.x;
  int b = blockIdx.x;
  const int nComb = (int)(MN / 2048);         // 1024
  if (b < nComb) {
    const size_t i8 = ((size_t)b * 256 + tid) * 8;
    short8 a  = *(const short8*)(parts_mn + i8);
    short8 bb = *(const short8*)(parts_mn + MN + i8);
    short8 c  = *(const short8*)(parts_mn + 2 * MN + i8);
    short8 d  = *(const short8*)(parts_mn + 3 * MN + i8);
    short8 o;
    #pragma unroll
    for (int r = 0; r < 8; ++r)
      o[r] = f2bf((bf2f(a[r]) + bf2f(bb[r])) + (bf2f(c[r]) + bf2f(d[r])));
    *(short8*)(Sb0 + i8) = o;
    return;
  }
  const int row = b - nComb;                  // 0..m-1
  const size_t MM = (size_t)m * m;
  float ss = 0.f;
  for (int c = tid; c < m; c += 256) {
    const size_t idx = (size_t)row * m + c;
    const float v = (bf2f(parts_mm[idx]) + bf2f(parts_mm[MM + idx]))
                  + (bf2f(parts_mm[2 * MM + idx]) + bf2f(parts_mm[3 * MM + idx]));
    ghat[idx] = f2bf(v);
    ss += v * v;
  }
  __shared__ float red[256];
  __shared__ int lastFlag;
  red[tid] = ss; __syncthreads();
  for (int o = 128; o > 0; o >>= 1) {
    if (tid < o) red[tid] += red[tid + o];
    __syncthreads();
  }
  if (tid == 0) {
    partial[row] = red[0];
    __threadfence();                               // release partial[row]
    const unsigned int old = atomicAdd(counter, 1u);
    lastFlag = (old == (unsigned int)(m - 1));
  }
  __syncthreads();
  if (!lastFlag) return;
  __threadfence();                                 // acquire all partial[]
  float s = 0.f;
  for (int i = tid; i < m; i += 256) s += partial[i];
  red[tid] = s; __syncthreads();
  for (int o = 128; o > 0; o >>= 1) {
    if (tid < o) red[tid] += red[tid + o];
    __syncthreads();
  }
  const float rn = 1.0f / (sqrtf(red[0]) + 1e-12f);
  for (int j = tid; j < n; j += 256) {
    const float v = 0.8f * lam[j] * rn;
    scal[j] = v;
    scal[n + j] = v * v;
  }
}

// ------- mega3: doubling0 (St1 = St0 + rs0.(St0@ghat)) + squaring ghat2 ------
__global__ void __launch_bounds__(256, 2)
k_mega3(const s16* __restrict__ Sb0, const s16* __restrict__ ghat,
        const float* __restrict__ scal0,
        s16* __restrict__ Sb1, s16* __restrict__ ghat2, int m, int n)
{
  __shared__ alignas(16) s16 lds[128 * 64];   // 16 KB both paths
  int b = blockIdx.x;
  const int nD0 = (n / 64) * (m / 64);        // 512
  if (b < nD0) {
    const int bxi = b % (n / 64), byi = b / (n / 64);
    gemm_body<64, 64, true>(Sb0, ghat, n, m, m, m, bxi, byi, 0,
                            scal0, Sb0, Sb1, nullptr, lds, lds + 64 * 64);
  } else {
    b -= nD0;
    const int bxi = b % (m / 64), byi = b / (m / 64);
    gemm_body<64, 64, false>(ghat, ghat, m, m, m, m, bxi, byi, 0,
                             nullptr, nullptr, ghat2, nullptr, lds, lds + 64 * 64);
  }
}

// ------- combine (KS=4, bf16 slices) -> fp32 out -----------------------------
__global__ void __launch_bounds__(256)
k_combine4b(const s16* __restrict__ parts, size_t MN, float* __restrict__ Cf)
{
  const size_t i8 = ((size_t)blockIdx.x * 256 + threadIdx.x) * 8;
  if (i8 >= MN) return;
  short8 a = *(const short8*)(parts + i8);
  short8 b = *(const short8*)(parts + MN + i8);
  short8 c = *(const short8*)(parts + 2 * MN + i8);
  short8 d = *(const short8*)(parts + 3 * MN + i8);
  f32x4 lo, hi;
  #pragma unroll
  for (int r = 0; r < 4; ++r) {
    lo[r] = (bf2f(a[r]) + bf2f(b[r])) + (bf2f(c[r]) + bf2f(d[r]));
    hi[r] = (bf2f(a[r + 4]) + bf2f(b[r + 4])) + (bf2f(c[r + 4]) + bf2f(d[r + 4]));
  }
  *(f32x4*)(Cf + i8) = lo;
  *(f32x4*)(Cf + i8 + 4) = hi;
}

// ------- conversion (round-12 form: 64r x 128c tiles, 2336 blocks) -----------
__device__ __forceinline__ void cvt_dual64(const float* __restrict__ in,
                                           s16* __restrict__ outp,
                                           s16* __restrict__ outt,
                                           int R, int C, int bx128, int by64,
                                           uint32_t (*t32)[65], int tid)
{
  const int bx = bx128 * 128, by = by64 * 64;
  const int u = tid & 15, v = tid >> 4;      // u: col-group (8 floats), v: 0..15
  const int c8 = u * 8;
  #pragma unroll
  for (int rr = 0; rr < 4; ++rr) {
    const int r = rr * 16 + v;
    const float* src = in + (size_t)(by + r) * C + bx + c8;
    const f32x4 a = *(const f32x4*)src;
    const f32x4 b = *(const f32x4*)(src + 4);
    s16 e[8];
    e[0] = f2bf(a[0]); e[1] = f2bf(a[1]); e[2] = f2bf(a[2]); e[3] = f2bf(a[3]);
    e[4] = f2bf(b[0]); e[5] = f2bf(b[1]); e[6] = f2bf(b[2]); e[7] = f2bf(b[3]);
    if (outp) {
      short8 o;
      #pragma unroll
      for (int j = 0; j < 8; ++j) o[j] = e[j];
      *(short8*)(outp + (size_t)(by + r) * C + bx + c8) = o;
    }
    #pragma unroll
    for (int jj = 0; jj < 4; ++jj)
      t32[r][u * 4 + jj] =
          ((uint32_t)(uint16_t)e[2 * jj]) | (((uint32_t)(uint16_t)e[2 * jj + 1]) << 16);
  }
  __syncthreads();
  const int uu = tid & 7, vv = tid >> 3;     // uu: row-chunk, vv: 0..31
  const int r8 = uu * 8;
  #pragma unroll
  for (int p = 0; p < 4; ++p) {
    const int c  = p * 32 + vv;
    const int w  = c >> 1;
    const int sh = (c & 1) * 16;
    short8 o;
    #pragma unroll
    for (int j = 0; j < 8; ++j)
      o[j] = (s16)(uint16_t)((t32[r8 + j][w] >> sh) & 0xffffu);
    *(short8*)(outt + (size_t)(bx + c) * R + by + r8) = o;
  }
}

__device__ __forceinline__ void cvt_plain64(const float* __restrict__ in,
                                            s16* __restrict__ outp,
                                            int C, int bx128, int by64, int tid)
{
  const int bx = bx128 * 128, by = by64 * 64;
  const int u = tid & 15, v = tid >> 4;
  const int c8 = u * 8;
  #pragma unroll
  for (int rr = 0; rr < 4; ++rr) {
    const int r = rr * 16 + v;
    const float* src = in + (size_t)(by + r) * C + bx + c8;
    const f32x4 a = *(const f32x4*)src;
    const f32x4 b = *(const f32x4*)(src + 4);
    short8 o;
    o[0] = f2bf(a[0]); o[1] = f2bf(a[1]); o[2] = f2bf(a[2]); o[3] = f2bf(a[3]);
    o[4] = f2bf(b[0]); o[5] = f2bf(b[1]); o[6] = f2bf(b[2]); o[7] = f2bf(b[3]);
    *(short8*)(outp + (size_t)(by + r) * C + bx + c8) = o;
  }
}

__global__ void __launch_bounds__(256)
k_cvt_all(const float* __restrict__ Q, const float* __restrict__ X,
          const float* __restrict__ F,
          s16* __restrict__ Qbf, s16* __restrict__ QTbf,
          s16* __restrict__ Xbf, s16* __restrict__ FTbf,
          unsigned int* __restrict__ counter, int m, int n)
{
  __shared__ uint32_t t32[64][65];           // 16.6 KB
  const int tid = threadIdx.x;
  int b = blockIdx.x;
  if (b == 0 && tid == 0) *counter = 0u;     // arm mega2's arrival counter
  const int qxx = n / 128, qyy = n / 64;
  const int nQ = qxx * qyy;                  // 2048
  const int nX = qxx * (m / 64);             // 256
  if (b < nQ) {
    cvt_dual64(Q, Qbf, QTbf, n, n, b % qxx, b / qxx, t32, tid);
  } else if ((b -= nQ) < nX) {
    cvt_plain64(X, Xbf, n, b % qxx, b / qxx, tid);
  } else {
    b -= nX;
    const int fx = m / 128;
    cvt_dual64(F, nullptr, FTbf, m, m, b % fx, b / fx, t32, tid);
  }
}

// ---------------- driver ----------------
extern "C" void kernel_launch(void* const* d_in, const int* in_sizes, int n_in,
                              void* d_out, int out_size, void* d_ws, size_t ws_size,
                              hipStream_t stream)
{
  const float* X   = (const float*)d_in[0];   // (m, n)
  const float* F   = (const float*)d_in[1];   // (m, m)
  const float* Q   = (const float*)d_in[2];   // (n, n)
  const float* lam = (const float*)d_in[3];   // (n,)

  int m = 1;
  while ((long long)m * m < (long long)in_sizes[1]) ++m;   // 512
  const int n = in_sizes[0] / m;                           // 4096
  const size_t MN = (size_t)m * n;
  const size_t MM = (size_t)m * m;

  char* w = (char*)d_ws;
  auto take = [&](size_t bytes) -> void* {
    char* p = w;
    w += (bytes + 255) & ~(size_t)255;
    return (void*)p;
  };

  // ~96 MB; ws ~256 MB. Only alias: Splain = Sb0 (dead after mega3).
  s16*   Qbf   = (s16*)take((size_t)n * n * 2);
  s16*   QTbf  = (s16*)take((size_t)n * n * 2);
  s16*   Xbf   = (s16*)take(MN * 2);
  s16*   FTbf  = (s16*)take(MM * 2);
  s16*   ghat  = (s16*)take(MM * 2);             // bf16(FtF)   (unscaled)
  s16*   ghat2 = (s16*)take(MM * 2);             // bf16(FtF^2) (unscaled)
  float* scal  = (float*)take((size_t)2 * n * 4);
  float* part  = (float*)take((size_t)m * 4);
  unsigned int* counter = (unsigned int*)take(256);
  s16*   Sb0   = (s16*)take(MN * 2);
  s16*   Sb1   = (s16*)take(MN * 2);
  s16*   parts_mn = (s16*)take(4 * MN * 2);
  s16*   parts_mm = (s16*)take(4 * MM * 2);
  (void)ws_size; (void)n_in; (void)out_size;

  s16* Splain = Sb0;

  const dim3 blk(256);
  const int nCvt = (n / 128) * (n / 64)          // Q dual
                 + (n / 128) * (m / 64)          // X plain
                 + (m / 128) * (m / 64);         // F dual (FT only)

  // 1) conversions (Q dual, X, F^T) + counter reset
  k_cvt_all<<<dim3(nCvt), blk, 0, stream>>>(Q, X, F, Qbf, QTbf, Xbf, FTbf,
                                            counter, m, n);

  // 2) mega1: St0 = Q^T X^T (128x64, MAP, KS=4) + FtF = F^T F (64x64, KS=4)
  k_mega1<<<dim3((n / 128) * (m / 64) * 4 + (m / 64) * (m / 64) * 4),
            blk, 0, stream>>>(QTbf, Xbf, FTbf, m, n, parts_mn, parts_mm);

  // 3) mega2: combine->Sb0 + combine+frob->ghat; last block -> rn, scal0/1
  k_mega2<<<dim3((unsigned)(MN / 2048) + m), blk, 0, stream>>>(
      parts_mn, parts_mm, lam, m, n, Sb0, ghat, part, scal, counter);

  // 4) mega3: doubling0 -> Sb1  +  squaring ghat2 = ghat @ ghat (KS=1)
  k_mega3<<<dim3((n / 64) * (m / 64) + (m / 64) * (m / 64)), blk, 0, stream>>>(
      Sb0, ghat, scal, Sb1, ghat2, m, n);

  // 5) doubling1: St2 = St1 + rs1.(St1@ghat2); emit S plain via obf_t
  gemm_t<64, 64, true, 0><<<dim3(n / 64, m / 64, 1), blk, 0, stream>>>(
      Sb1, ghat2, n, m, m, m, 0, 0, scal + n, Sb1, nullptr, Splain);

  // 6) st7: Z = S @ Q^T (64x128, MAP, KS=4) -> bf16 partials
  gemm_t<64, 128, false, 1><<<dim3((n / 128) * (m / 64) * 4), blk, 0, stream>>>(
      Splain, Qbf, m, n, n, n / 4, n / 128, m / 64, nullptr, nullptr, parts_mn, nullptr);

  // 7) final combine -> d_out fp32
  k_combine4b<<<dim3((unsigned)(MN / 2048)), blk, 0, stream>>>(
      parts_mn, MN, (float*)d_out);
}

// Round 14
// 130.811 us; speedup vs baseline: 1.0264x; 1.0264x over previous
//
#include <hip/hip_runtime.h>
#include <stdint.h>

typedef short s16;
typedef __attribute__((ext_vector_type(8))) short short8;  // 8 bf16 (4 VGPRs)
typedef __attribute__((ext_vector_type(4))) float f32x4;

__device__ __forceinline__ s16 f2bf(float f) {
  union { float f; uint32_t u; } v; v.f = f;
  uint32_t u = v.u;
  uint32_t r = (u + 0x7fffu + ((u >> 16) & 1u)) >> 16;  // RNE
  return (s16)(uint16_t)r;
}
__device__ __forceinline__ float bf2f(s16 b) {
  union { uint32_t u; float f; } v; v.u = ((uint32_t)(uint16_t)b) << 16;
  return v.f;
}

#define GLOBAL_AS __attribute__((address_space(1)))
#define LDS_AS    __attribute__((address_space(3)))
__device__ __forceinline__ void gload_lds16(const void* g, void* l) {
  __builtin_amdgcn_global_load_lds((const GLOBAL_AS uint32_t*)g, (LDS_AS uint32_t*)l, 16, 0, 0);
}

// ---------------- GEMM body: C(MxN) = A(MxK,row) @ B, B given as BT(NxK,row) --
// PROVEN single-buffer 2-barrier K-loop, BK=64, XOR-swizzled LDS via
// pre-swizzled global source. Verbatim since round 3.
template<int BM_, int BN_, bool SX>
__device__ __forceinline__ void
gemm_body(const s16* __restrict__ A, const s16* __restrict__ BT,
          int M, int N, int K, int Kc, int bxi, int byi, int bzi,
          const float* __restrict__ rowscale,
          const s16* __restrict__ addend_bf,   // read-only; may equal A
          s16* __restrict__ obf_n, s16* __restrict__ obf_t,
          s16* lta, s16* ltb)
{
  constexpr int SWA = BM_ / 32;
  constexpr int SWB = BN_ / 32;
  constexpr int WM  = BM_ / 2;
  constexpr int WN  = BN_ / 2;
  constexpr int IM  = WM / 16;
  constexpr int JN  = WN / 16;

  const int tid  = threadIdx.x;
  const int lane = tid & 63;
  const int wave = tid >> 6;
  const int wr = wave >> 1, wc = wave & 1;
  const int bm0 = (SX ? bxi : byi) * BM_;
  const int bn0 = (SX ? byi : bxi) * BN_;
  const int k0  = bzi * Kc;

  f32x4 acc[IM][JN];
  #pragma unroll
  for (int i = 0; i < IM; ++i)
    #pragma unroll
    for (int j = 0; j < JN; ++j)
      #pragma unroll
      for (int r = 0; r < 4; ++r) acc[i][j][r] = 0.0f;

  const int lrow = lane >> 3;
  const int lke  = ((lane & 7) ^ lrow) * 8;
  const s16* Ab = A  + (size_t)(bm0 + wave * 8 + lrow) * K + k0 + lke;
  const s16* Bb = BT + (size_t)(bn0 + wave * 8 + lrow) * K + k0 + lke;

  const int fr = lane & 15;
  const int k8 = (lane >> 4) * 8;
  const int sw = (fr & 7) * 8;       // read-side XOR: row&7 == fr&7

  const int nt = Kc / 64;
  for (int t = 0; t < nt; ++t) {
    const int ko = t * 64;
    #pragma unroll
    for (int s = 0; s < SWA; ++s)
      gload_lds16(Ab + (size_t)s * 32 * K + ko, &lta[s * 2048 + wave * 512]);
    #pragma unroll
    for (int s = 0; s < SWB; ++s)
      gload_lds16(Bb + (size_t)s * 32 * K + ko, &ltb[s * 2048 + wave * 512]);
    __syncthreads();   // drains vmcnt(0): tile fully staged

    short8 af[2][IM], bfv[2][JN];
    #pragma unroll
    for (int kk = 0; kk < 2; ++kk) {
      #pragma unroll
      for (int i = 0; i < IM; ++i)
        af[kk][i] = *(const short8*)&lta[(wr * WM + i * 16 + fr) * 64 + ((kk * 32 + k8) ^ sw)];
      #pragma unroll
      for (int j = 0; j < JN; ++j)
        bfv[kk][j] = *(const short8*)&ltb[(wc * WN + j * 16 + fr) * 64 + ((kk * 32 + k8) ^ sw)];
    }
    #pragma unroll
    for (int kk = 0; kk < 2; ++kk)
      #pragma unroll
      for (int i = 0; i < IM; ++i)
        #pragma unroll
        for (int j = 0; j < JN; ++j)
          acc[i][j] = __builtin_amdgcn_mfma_f32_16x16x32_bf16(af[kk][i], bfv[kk][j], acc[i][j], 0, 0, 0);
    __syncthreads();   // all waves done reading before next tile overwrites
  }

  // epilogue — C/D layout: col = lane&15, row = (lane>>4)*4 + reg
  s16* on = obf_n ? obf_n + (size_t)bzi * M * N : nullptr;
  const int r0 = (lane >> 4) * 4;
  const int cl = lane & 15;
  #pragma unroll
  for (int i = 0; i < IM; ++i) {
    const int gm = bm0 + wr * WM + i * 16 + r0;
    #pragma unroll
    for (int j = 0; j < JN; ++j) {
      const int gn = bn0 + wc * WN + j * 16 + cl;
      #pragma unroll
      for (int r = 0; r < 4; ++r) {
        const size_t idx = (size_t)(gm + r) * N + gn;
        float v = acc[i][j][r];
        if (rowscale)  v *= rowscale[gm + r];
        if (addend_bf) v += bf2f(addend_bf[idx]);
        if (on)    on[idx] = f2bf(v);
        if (obf_t) obf_t[(size_t)gn * M + (gm + r)] = f2bf(v);
      }
    }
  }
}

// ------- standalone GEMM wrapper (MAP=1: XCD-aware 1D decode) ----------------
template<int BM_, int BN_, bool SX, int MAP>
__global__ void __launch_bounds__(256, 2)
gemm_t(const s16* __restrict__ A, const s16* __restrict__ BT,
       int M, int N, int K, int Kc, int gx,
       const float* __restrict__ rowscale,
       const s16* __restrict__ addend_bf,
       s16* __restrict__ obf_n, s16* __restrict__ obf_t)
{
  __shared__ alignas(16) s16 lds[BM_ * 64 + BN_ * 64];
  int bxi, byi, bzi;
  if (MAP == 1) {
    const int fid = blockIdx.x;
    const int c  = fid & 7;
    const int tt = fid >> 3;
    const int gxh = gx >> 1;
    bzi = c & 3;
    bxi = (c >> 2) * gxh + tt % gxh;
    byi = tt / gxh;
  } else {
    bxi = blockIdx.x; byi = blockIdx.y; bzi = blockIdx.z;
  }
  gemm_body<BM_, BN_, SX>(A, BT, M, N, K, Kc, bxi, byi, bzi,
                          rowscale, addend_bf, obf_n, obf_t, lds, lds + BM_ * 64);
}

// ------- mega1: st5 GEMM (St0 partials) + FtF GEMM (partials) ----------------
__global__ void __launch_bounds__(256, 2)
k_mega1(const s16* __restrict__ QT, const s16* __restrict__ Xb,
        const s16* __restrict__ FT, int m, int n,
        s16* __restrict__ parts_mn, s16* __restrict__ parts_mm)
{
  __shared__ alignas(16) s16 lds[192 * 64];   // 24.5 KB (max of both paths)
  int b = blockIdx.x;
  const int gx = n / 128;
  const int nSt5 = gx * (m / 64) * 4;         // 1024
  if (b < nSt5) {
    const int c = b & 7, tt = b >> 3, gxh = gx >> 1;
    const int bzi = c & 3, bxi = (c >> 2) * gxh + tt % gxh, byi = tt / gxh;
    gemm_body<128, 64, true>(QT, Xb, n, m, n, n / 4, bxi, byi, bzi,
                             nullptr, nullptr, parts_mn, nullptr,
                             lds, lds + 128 * 64);
  } else {
    b -= nSt5;
    const int gm = m / 64;                    // 8
    const int bxi = b % gm, byi = (b / gm) % gm, bzi = b / (gm * gm);
    gemm_body<64, 64, false>(FT, FT, m, m, m, m / 4, bxi, byi, bzi,
                             nullptr, nullptr, parts_mm, nullptr,
                             lds, lds + 64 * 64);
  }
}

// ------- mega2: combine(St0)->Sb0  +  combine(FtF)->ghat + Frobenius ---------
// Last-arriving frob block computes rn = 1/(||FtF||_F+eps) and folds it into
// the doubling rowscales scal0 = 0.8*lam*rn, scal1 = scal0^2.
__global__ void __launch_bounds__(256)
k_mega2(const s16* __restrict__ parts_mn, const s16* __restrict__ parts_mm,
        const float* __restrict__ lam, int m, int n,
        s16* __restrict__ Sb0, s16* __restrict__ ghat,
        float* __restrict__ partial, float* __restrict__ scal,
        unsigned int* __restrict__ counter)
{
  const size_t MN = (size_t)m * n;
  const int tid = threadIdx.x;
  int b = blockIdx.x;
  const int nComb = (int)(MN / 2048);         // 1024
  if (b < nComb) {
    const size_t i8 = ((size_t)b * 256 + tid) * 8;
    short8 a  = *(const short8*)(parts_mn + i8);
    short8 bb = *(const short8*)(parts_mn + MN + i8);
    short8 c  = *(const short8*)(parts_mn + 2 * MN + i8);
    short8 d  = *(const short8*)(parts_mn + 3 * MN + i8);
    short8 o;
    #pragma unroll
    for (int r = 0; r < 8; ++r)
      o[r] = f2bf((bf2f(a[r]) + bf2f(bb[r])) + (bf2f(c[r]) + bf2f(d[r])));
    *(short8*)(Sb0 + i8) = o;
    return;
  }
  const int row = b - nComb;                  // 0..m-1
  const size_t MM = (size_t)m * m;
  float ss = 0.f;
  for (int c = tid; c < m; c += 256) {
    const size_t idx = (size_t)row * m + c;
    const float v = (bf2f(parts_mm[idx]) + bf2f(parts_mm[MM + idx]))
                  + (bf2f(parts_mm[2 * MM + idx]) + bf2f(parts_mm[3 * MM + idx]));
    ghat[idx] = f2bf(v);
    ss += v * v;
  }
  __shared__ float red[256];
  __shared__ int lastFlag;
  red[tid] = ss; __syncthreads();
  for (int o = 128; o > 0; o >>= 1) {
    if (tid < o) red[tid] += red[tid + o];
    __syncthreads();
  }
  if (tid == 0) {
    partial[row] = red[0];
    __threadfence();                               // release partial[row]
    const unsigned int old = atomicAdd(counter, 1u);
    lastFlag = (old == (unsigned int)(m - 1));
  }
  __syncthreads();
  if (!lastFlag) return;
  __threadfence();                                 // acquire all partial[]
  float s = 0.f;
  for (int i = tid; i < m; i += 256) s += partial[i];
  red[tid] = s; __syncthreads();
  for (int o = 128; o > 0; o >>= 1) {
    if (tid < o) red[tid] += red[tid + o];
    __syncthreads();
  }
  const float rn = 1.0f / (sqrtf(red[0]) + 1e-12f);
  for (int j = tid; j < n; j += 256) {
    const float v = 0.8f * lam[j] * rn;
    scal[j] = v;
    scal[n + j] = v * v;
  }
}

// ------- mega3: doubling0 (St1 = St0 + rs0.(St0@ghat)) + squaring ghat2 ------
__global__ void __launch_bounds__(256, 2)
k_mega3(const s16* __restrict__ Sb0, const s16* __restrict__ ghat,
        const float* __restrict__ scal0,
        s16* __restrict__ Sb1, s16* __restrict__ ghat2, int m, int n)
{
  __shared__ alignas(16) s16 lds[128 * 64];   // 16 KB both paths
  int b = blockIdx.x;
  const int nD0 = (n / 64) * (m / 64);        // 512
  if (b < nD0) {
    const int bxi = b % (n / 64), byi = b / (n / 64);
    gemm_body<64, 64, true>(Sb0, ghat, n, m, m, m, bxi, byi, 0,
                            scal0, Sb0, Sb1, nullptr, lds, lds + 64 * 64);
  } else {
    b -= nD0;
    const int bxi = b % (m / 64), byi = b / (m / 64);
    gemm_body<64, 64, false>(ghat, ghat, m, m, m, m, bxi, byi, 0,
                             nullptr, nullptr, ghat2, nullptr, lds, lds + 64 * 64);
  }
}

// ------- combine (KS=4, bf16 slices) -> fp32 out -----------------------------
__global__ void __launch_bounds__(256)
k_combine4b(const s16* __restrict__ parts, size_t MN, float* __restrict__ Cf)
{
  const size_t i8 = ((size_t)blockIdx.x * 256 + threadIdx.x) * 8;
  if (i8 >= MN) return;
  short8 a = *(const short8*)(parts + i8);
  short8 b = *(const short8*)(parts + MN + i8);
  short8 c = *(const short8*)(parts + 2 * MN + i8);
  short8 d = *(const short8*)(parts + 3 * MN + i8);
  f32x4 lo, hi;
  #pragma unroll
  for (int r = 0; r < 4; ++r) {
    lo[r] = (bf2f(a[r]) + bf2f(b[r])) + (bf2f(c[r]) + bf2f(d[r]));
    hi[r] = (bf2f(a[r + 4]) + bf2f(b[r + 4])) + (bf2f(c[r + 4]) + bf2f(d[r + 4]));
  }
  *(f32x4*)(Cf + i8) = lo;
  *(f32x4*)(Cf + i8 + 4) = hi;
}

// ------- conversion ----------------------------------------------------------
// Round-11 best-measured form: dual-output tiles as two 128r x 64c halves over
// a 16.9 KB LDS buffer (u32 [128][33], b32 stores, XOR-4 skew). Plain-only (X)
// keeps the full-width streaming path (no LDS).
__device__ __forceinline__ void cvt_dual_h(const float* __restrict__ in,
                                           s16* __restrict__ outp,
                                           s16* __restrict__ outt,
                                           int R, int C, int bx128, int by128,
                                           uint32_t (*t32)[33], int tid)
{
  const int bx = bx128 * 128, by = by128 * 128;
  const int u  = tid & 7;          // col-group in half: 8 floats each
  const int vr = tid >> 3;         // 0..31 row within sweep
  const int uu = tid & 15;         // phase-2: row-group (8 rows)
  const int vv = tid >> 4;         // phase-2: 0..15
  const int k4r = (uu >> 2) << 2;  // phase-2 XOR: ((r8+j)>>5)<<2 == (uu>>2)<<2
  #pragma unroll
  for (int h = 0; h < 2; ++h) {
    if (h) __syncthreads();        // reuse LDS across halves
    const int c8 = h * 64 + u * 8;
    #pragma unroll
    for (int rr = 0; rr < 4; ++rr) {
      const int r = rr * 32 + vr;
      const float* src = in + (size_t)(by + r) * C + bx + c8;
      const f32x4 a = *(const f32x4*)src;
      const f32x4 b = *(const f32x4*)(src + 4);
      s16 e[8];
      e[0] = f2bf(a[0]); e[1] = f2bf(a[1]); e[2] = f2bf(a[2]); e[3] = f2bf(a[3]);
      e[4] = f2bf(b[0]); e[5] = f2bf(b[1]); e[6] = f2bf(b[2]); e[7] = f2bf(b[3]);
      if (outp) {
        short8 o;
        #pragma unroll
        for (int j = 0; j < 8; ++j) o[j] = e[j];
        *(short8*)(outp + (size_t)(by + r) * C + bx + c8) = o;
      }
      const int k4 = rr << 2;      // (r>>5)<<2 since r = rr*32 + vr, vr<32
      #pragma unroll
      for (int jj = 0; jj < 4; ++jj)
        t32[r][(u * 4 + jj) ^ k4] =
            ((uint32_t)(uint16_t)e[2 * jj]) | (((uint32_t)(uint16_t)e[2 * jj + 1]) << 16);
    }
    __syncthreads();
    const int r8 = uu * 8;
    #pragma unroll
    for (int p = 0; p < 4; ++p) {
      const int cl = p * 16 + vv;          // 0..63 within half
      const int c  = h * 64 + cl;
      const int w  = cl >> 1;
      const int sh = (cl & 1) * 16;
      short8 o;
      #pragma unroll
      for (int j = 0; j < 8; ++j)
        o[j] = (s16)(uint16_t)((t32[r8 + j][w ^ k4r] >> sh) & 0xffffu);
      *(short8*)(outt + (size_t)(bx + c) * R + by + r8) = o;
    }
  }
}

__device__ __forceinline__ void cvt_plain(const float* __restrict__ in,
                                          s16* __restrict__ outp,
                                          int C, int bx128, int by128, int tid)
{
  const int bx = bx128 * 128, by = by128 * 128;
  const int u = tid & 15, v = tid >> 4;
  const int c8 = u * 8;
  #pragma unroll
  for (int rr = 0; rr < 8; ++rr) {
    const int r = rr * 16 + v;
    const float* src = in + (size_t)(by + r) * C + bx + c8;
    const f32x4 a = *(const f32x4*)src;
    const f32x4 b = *(const f32x4*)(src + 4);
    short8 o;
    o[0] = f2bf(a[0]); o[1] = f2bf(a[1]); o[2] = f2bf(a[2]); o[3] = f2bf(a[3]);
    o[4] = f2bf(b[0]); o[5] = f2bf(b[1]); o[6] = f2bf(b[2]); o[7] = f2bf(b[3]);
    *(short8*)(outp + (size_t)(by + r) * C + bx + c8) = o;
  }
}

__global__ void __launch_bounds__(256)
k_cvt_all(const float* __restrict__ Q, const float* __restrict__ X,
          const float* __restrict__ F,
          s16* __restrict__ Qbf, s16* __restrict__ QTbf,
          s16* __restrict__ Xbf, s16* __restrict__ FTbf,
          unsigned int* __restrict__ counter, int m, int n)
{
  __shared__ uint32_t t32[128][33];          // 16.9 KB -> 8 blocks/CU
  const int tid = threadIdx.x;
  int b = blockIdx.x;
  if (b == 0 && tid == 0) *counter = 0u;     // arm mega2's arrival counter
  const int qx = n / 128;
  const int mx = m / 128;
  const int nQ = qx * qx;
  const int nX = qx * mx;
  if (b < nQ) {
    cvt_dual_h(Q, Qbf, QTbf, n, n, b % qx, b / qx, t32, tid);
  } else if ((b -= nQ) < nX) {
    cvt_plain(X, Xbf, n, b % qx, b / qx, tid);
  } else {
    b -= nX;
    cvt_dual_h(F, nullptr, FTbf, m, m, b % mx, b / mx, t32, tid);
  }
}

// ---------------- driver ----------------
extern "C" void kernel_launch(void* const* d_in, const int* in_sizes, int n_in,
                              void* d_out, int out_size, void* d_ws, size_t ws_size,
                              hipStream_t stream)
{
  const float* X   = (const float*)d_in[0];   // (m, n)
  const float* F   = (const float*)d_in[1];   // (m, m)
  const float* Q   = (const float*)d_in[2];   // (n, n)
  const float* lam = (const float*)d_in[3];   // (n,)

  int m = 1;
  while ((long long)m * m < (long long)in_sizes[1]) ++m;   // 512
  const int n = in_sizes[0] / m;                           // 4096
  const size_t MN = (size_t)m * n;
  const size_t MM = (size_t)m * m;

  char* w = (char*)d_ws;
  auto take = [&](size_t bytes) -> void* {
    char* p = w;
    w += (bytes + 255) & ~(size_t)255;
    return (void*)p;
  };

  // ~96 MB; ws ~256 MB. Only alias: Splain = Sb0 (dead after mega3).
  s16*   Qbf   = (s16*)take((size_t)n * n * 2);
  s16*   QTbf  = (s16*)take((size_t)n * n * 2);
  s16*   Xbf   = (s16*)take(MN * 2);
  s16*   FTbf  = (s16*)take(MM * 2);
  s16*   ghat  = (s16*)take(MM * 2);             // bf16(FtF)   (unscaled)
  s16*   ghat2 = (s16*)take(MM * 2);             // bf16(FtF^2) (unscaled)
  float* scal  = (float*)take((size_t)2 * n * 4);
  float* part  = (float*)take((size_t)m * 4);
  unsigned int* counter = (unsigned int*)take(256);
  s16*   Sb0   = (s16*)take(MN * 2);
  s16*   Sb1   = (s16*)take(MN * 2);
  s16*   parts_mn = (s16*)take(4 * MN * 2);
  s16*   parts_mm = (s16*)take(4 * MM * 2);
  (void)ws_size; (void)n_in; (void)out_size;

  s16* Splain = Sb0;

  const dim3 blk(256);
  const int nCvt = (n / 128) * (n / 128) + (n / 128) * (m / 128)
                 + (m / 128) * (m / 128);

  // 1) conversions (Q dual, X, F^T) + counter reset
  k_cvt_all<<<dim3(nCvt), blk, 0, stream>>>(Q, X, F, Qbf, QTbf, Xbf, FTbf,
                                            counter, m, n);

  // 2) mega1: St0 = Q^T X^T (128x64, MAP, KS=4) + FtF = F^T F (64x64, KS=4)
  k_mega1<<<dim3((n / 128) * (m / 64) * 4 + (m / 64) * (m / 64) * 4),
            blk, 0, stream>>>(QTbf, Xbf, FTbf, m, n, parts_mn, parts_mm);

  // 3) mega2: combine->Sb0 + combine+frob->ghat; last block -> rn, scal0/1
  k_mega2<<<dim3((unsigned)(MN / 2048) + m), blk, 0, stream>>>(
      parts_mn, parts_mm, lam, m, n, Sb0, ghat, part, scal, counter);

  // 4) mega3: doubling0 -> Sb1  +  squaring ghat2 = ghat @ ghat (KS=1)
  k_mega3<<<dim3((n / 64) * (m / 64) + (m / 64) * (m / 64)), blk, 0, stream>>>(
      Sb0, ghat, scal, Sb1, ghat2, m, n);

  // 5) doubling1: St2 = St1 + rs1.(St1@ghat2); emit S plain via obf_t
  gemm_t<64, 64, true, 0><<<dim3(n / 64, m / 64, 1), blk, 0, stream>>>(
      Sb1, ghat2, n, m, m, m, 0, scal + n, Sb1, nullptr, Splain);

  // 6) st7: Z = S @ Q^T (64x128, MAP, KS=4) -> bf16 partials
  gemm_t<64, 128, false, 1><<<dim3((n / 128) * (m / 64) * 4), blk, 0, stream>>>(
      Splain, Qbf, m, n, n, n / 4, n / 128, nullptr, nullptr, parts_mn, nullptr);

  // 7) final combine -> d_out fp32
  k_combine4b<<<dim3((unsigned)(MN / 2048)), blk, 0, stream>>>(
      parts_mn, MN, (float*)d_out);
}